// Round 9
// baseline (195.611 us; speedup 1.0000x reference)
//
#include <hip/hip_runtime.h>
#include <hip/hip_bf16.h>
#include <math.h>

// Problem dims (fixed by reference)
#define BB 4
#define TT 1024
#define DD 1024
#define HPS 4          // heads per scale
#define C0 21
#define C1 41
#define N0 (HPS * C0)  // 84
#define N1 (HPS * C1)  // 164
#define BT (BB * TT)   // 4096
#define TB2 32         // t-tile for window kernel (512 blocks -> 2/CU)
#define HALO 20
#define HB2 (TB2 + 2 * HALO)  // 72 rows staged

typedef unsigned int uint;
typedef __bf16 bf16x8 __attribute__((ext_vector_type(8)));
typedef float f32x4 __attribute__((ext_vector_type(4)));

__device__ __forceinline__ ushort f2bf(float f) {
    union { float f; uint u; } v; v.f = f;
    uint u = v.u;
    uint r = (u + 0x7FFFu + ((u >> 16) & 1u)) >> 16;
    return (ushort)r;
}
__device__ __forceinline__ float bf2f(ushort s) {
    union { uint u; float f; } v; v.u = ((uint)s) << 16;
    return v.f;
}

// ---------------- fused conversion kernel (query + weights, R7 structure) ----------------
#define RQ  4096
#define R1  (RQ + 2048)
#define R2  (R1 + 1024)
#define R3  (R2 + 96)
#define R4  (R3 + 192)

// Transpose [K][Nin] f32 -> bf16 [row][K] where row = (n/hs)*64 + roff + n%hs.
// hs >= Nin gives linear row = n (W_qv, W_out). For W2 the per-head remap packs
// head h's columns into rows h*64 + roff.. for the fused attn kernel.
__device__ __forceinline__ void transpose_tile(
    const float* __restrict__ in, ushort* __restrict__ out,
    int K, int Nin, int nx, int ky, int tid, int hs, int roff)
{
    __shared__ float tile[32][33];
    const int tx = tid & 31;
    const int ty = tid >> 5;   // 0..7
    const int n0 = nx * 32;
    const int k0 = ky * 32;
    #pragma unroll
    for (int i = 0; i < 4; i++) {
        int k = k0 + ty + i * 8;
        int n = n0 + tx;
        float v = (k < K && n < Nin) ? in[(size_t)k * Nin + n] : 0.0f;
        tile[ty + i * 8][tx] = v;
    }
    __syncthreads();
    #pragma unroll
    for (int i = 0; i < 4; i++) {
        int n = n0 + ty + i * 8;
        int k = k0 + tx;
        if (n < Nin && k < K) {
            int row = (n / hs) * 64 + roff + (n % hs);
            out[(size_t)row * K + k] = f2bf(tile[tx][ty + i * 8]);
        }
    }
}

__global__ __launch_bounds__(256) void convert_all(
    const float* __restrict__ query, ushort* __restrict__ query_bf,
    const float* __restrict__ W_qv,  ushort* __restrict__ WqvT,
    const float* __restrict__ W_out, ushort* __restrict__ WoutT,
    const float* __restrict__ W2_0, const float* __restrict__ W2_1,
    ushort* __restrict__ W2Tph)
{
    const int blk = blockIdx.x;
    const int tid = threadIdx.x;
    if (blk < RQ) {
        int i = blk * 1024 + tid * 4;
        float4 v = *(const float4*)(query + i);
        ushort4 o;
        o.x = f2bf(v.x); o.y = f2bf(v.y); o.z = f2bf(v.z); o.w = f2bf(v.w);
        *(ushort4*)(query_bf + i) = o;
    } else if (blk < R1) {
        int idx = blk - RQ;                // 64 x 32 tiles, linear rows
        transpose_tile(W_qv, WqvT, DD, 2 * DD, idx & 63, idx >> 6, tid, 2 * DD, 0);
    } else if (blk < R2) {
        int idx = blk - R1;                // 32 x 32 tiles, linear rows
        transpose_tile(W_out, WoutT, DD, DD, idx & 31, idx >> 5, tid, DD, 0);
    } else if (blk < R3) {
        int idx = blk - R2;                // 3 x 32: scale0 -> rows h*64 + 0..20
        transpose_tile(W2_0, W2Tph, DD, N0, idx % 3, idx / 3, tid, C0, 0);
    } else {
        int idx = blk - R3;                // 6 x 32: scale1 -> rows h*64 + 21..61
        transpose_tile(W2_1, W2Tph, DD, N1, idx % 6, idx / 6, tid, C1, C0);
    }
}

// XCD-chunked bijective tile remap (T1). Requires ntile % 8 == 0.
__device__ __forceinline__ int xcd_chunk(int blk, int nblk) {
    return (blk & 7) * (nblk >> 3) + (blk >> 3);
}

// ------ bf16 MFMA GEMM, 8-wave (512-thr) block, 128xNT tile, BK=64 dbuf ------
// A: [M][K] bf16 row-major. Bt: [N][K] bf16 row-major (both via global_load_lds
// with pre-swizzled source — reverted R8's reg-staged f32 A: it was slower,
// per m151 gload_lds > reg-staging at this tile size). K,klen multiples of 64.
// 8 waves in 2(M) x 4(N); wave owns 64 x NT/4. MINW = min waves/EU for the
// occupancy cap: NT=128 (64 KB LDS) -> MINW=4 (2 blocks/CU, LDS-capped anyway);
// NT=64 (48 KB LDS) -> MINW=6 (3 blocks/CU = 24 waves, VGPR capped at 84).
// LDS per buffer: [row][slot 0..7][8 ushort]; slot (r,c) holds global chunk
// c^(r&7). Fragment read xor fx=l15&7 -> 2-way bank aliasing (free).
// mode 0: Cf[row*ldc+col] = acc
// mode 2: col<DD -> Cb[row*DD+col]=bf16(relu(acc)); else Cv[row*DD+col-DD]=bf16(acc)
template<int NT, int MINW>
__global__ __launch_bounds__(512, MINW) void gemm_mfma(
    const ushort* __restrict__ A, const ushort* __restrict__ Bt,
    int K, int klen,
    float* __restrict__ Cf, ushort* __restrict__ Cb, ushort* __restrict__ Cv,
    int mode, int ldc)
{
    constexpr int MT = 128;
    constexpr int MR = 4;          // 64 / 16
    constexpr int NR = NT / 64;    // wave N-frags: NT=128 -> 2, NT=64 -> 1
    __shared__ ushort As[2][MT * 64];   // 2 x 16 KB
    __shared__ ushort Bs[2][NT * 64];   // 2 x (16 or 8) KB

    const int tid = threadIdx.x;
    const int wv  = tid >> 6;          // 0..7
    const int ln  = tid & 63;

    const int ntile = gridDim.x * gridDim.y;
    const int tile  = xcd_chunk(blockIdx.y * gridDim.x + blockIdx.x, ntile);
    const int bx = tile % gridDim.x;
    const int by = tile / gridDim.x;
    const int row0 = by * MT;
    const int col0 = bx * NT;

    const int wr = (wv >> 2) * 64;        // wave M offset: 0/64
    const int wc = (wv & 3) * (NT / 4);   // wave N offset
    const int l15 = ln & 15;
    const int lq  = ln >> 4;              // 0..3

    f32x4 acc[MR][NR];
    #pragma unroll
    for (int i = 0; i < MR; i++)
        #pragma unroll
        for (int j = 0; j < NR; j++)
            acc[i][j] = (f32x4){0.f, 0.f, 0.f, 0.f};

    const int rsub = ln >> 3;             // 0..7
    const int cg   = (ln & 7) ^ rsub;     // pre-swizzled global chunk
    const ushort* gA = A  + (size_t)(row0 + wv * 8 + rsub) * K + cg * 8;
    const ushort* gB = Bt + (size_t)(col0 + wv * 8 + rsub) * K + cg * 8;
    const int fx = l15 & 7;
    const int nt = klen / 64;

    auto STAGE = [&](int buf, int kk) {
        #pragma unroll
        for (int i = 0; i < 2; i++) {     // A: 2 instrs cover 128 rows
            __builtin_amdgcn_global_load_lds(
                (const __attribute__((address_space(1))) void*)(gA + (size_t)i * 64 * K + kk),
                (__attribute__((address_space(3))) void*)(&As[buf][(i * 64 + wv * 8) * 64]),
                16, 0, 0);
        }
        #pragma unroll
        for (int i = 0; i < NT / 64; i++) {  // B: NT/64 instrs
            __builtin_amdgcn_global_load_lds(
                (const __attribute__((address_space(1))) void*)(gB + (size_t)i * 64 * K + kk),
                (__attribute__((address_space(3))) void*)(&Bs[buf][(i * 64 + wv * 8) * 64]),
                16, 0, 0);
        }
    };

    auto COMPUTE = [&](int buf) {
        #pragma unroll
        for (int s = 0; s < 2; s++) {
            const int ca = ((s * 4 + lq) ^ fx) * 8;
            bf16x8 af[MR], bfr[NR];
            #pragma unroll
            for (int mi = 0; mi < MR; mi++)
                af[mi] = *(const bf16x8*)&As[buf][(wr + mi * 16 + l15) * 64 + ca];
            #pragma unroll
            for (int ni = 0; ni < NR; ni++)
                bfr[ni] = *(const bf16x8*)&Bs[buf][(wc + ni * 16 + l15) * 64 + ca];
            #pragma unroll
            for (int mi = 0; mi < MR; mi++)
                #pragma unroll
                for (int ni = 0; ni < NR; ni++)
                    acc[mi][ni] = __builtin_amdgcn_mfma_f32_16x16x32_bf16(
                        af[mi], bfr[ni], acc[mi][ni], 0, 0, 0);
        }
    };

    int cur = 0;
    STAGE(0, 0);
    __syncthreads();
    for (int t = 0; t < nt; ++t) {
        const bool more = (t + 1 < nt);
        if (more) STAGE(cur ^ 1, (t + 1) * 64);
        COMPUTE(cur);
        if (more) __syncthreads();
        cur ^= 1;
    }

    // Epilogue. D layout: col = lane&15, row = (lane>>4)*4 + reg.
    #pragma unroll
    for (int mi = 0; mi < MR; mi++) {
        #pragma unroll
        for (int ni = 0; ni < NR; ni++) {
            #pragma unroll
            for (int r = 0; r < 4; r++) {
                int row = row0 + wr + mi * 16 + lq * 4 + r;
                int col = col0 + wc + ni * 16 + l15;
                float v = acc[mi][ni][r];
                if (mode == 0) {
                    Cf[(size_t)row * ldc + col] = v;
                } else {
                    if (col < DD) Cb[(size_t)row * DD + col] = f2bf(fmaxf(v, 0.0f));
                    else          Cv[(size_t)row * DD + (col - DD)] = f2bf(v);
                }
            }
        }
    }
}

// ---- fused logits + softmax + sliding-window kernel, 8-wave (512-thr) ----
// 512 blocks = (b, t-tile of 32, head), 512 threads, ~75 KB dynamic LDS.
// TLP fix (same mechanism as the R6 GEMM win): 256-thr blocks gave only
// 8 waves/CU (2 blocks x 4 waves, LDS-capped); 512-thr blocks give 16 waves/CU
// at the same 2 blocks/CU. QK re-tiled: 8 waves x one 16x16 frag (2M x 4N).
#define LOFF_VS 0
#define LOFF_QS (LOFF_VS + HB2 * 256 * 2)            // 36864
#define LOFF_WS (LOFF_QS + 2 * TB2 * 64 * 2)         // +8192 = 45056
#define LOFF_LS (LOFF_WS + 2 * 64 * 64 * 2)          // +16384 = 61440
#define LOFF_CW (LOFF_LS + TB2 * 65 * 4)             // +8320 = 69760
#define LDS_TOTAL (LOFF_CW + TB2 * 42 * 4)           // +5376 = 75136

__global__ __launch_bounds__(512, 4) void attn_fused_kernel(
    const ushort* __restrict__ reluq,
    const ushort* __restrict__ W2Tph,   // [4][64][1024] bf16
    const ushort* __restrict__ v,
    const float* __restrict__ scale_w,
    ushort* __restrict__ x)
{
    extern __shared__ __attribute__((aligned(16))) char smem[];
    ushort (*vs)[256] = (ushort (*)[256])(smem + LOFF_VS);
    ushort* qs = (ushort*)(smem + LOFF_QS);          // [2][32*64]
    ushort* ws2 = (ushort*)(smem + LOFF_WS);         // [2][64*64]
    float  (*Ls)[65] = (float (*)[65])(smem + LOFF_LS);
    float  (*cw)[42] = (float (*)[42])(smem + LOFF_CW);

    const int blk = blockIdx.x;       // 512 blocks
    const int h  = blk & 3;
    const int tt = (blk >> 2) & 31;
    const int b  = blk >> 7;
    const int t0 = tt * TB2;
    const int tid = threadIdx.x;      // 0..511
    const int bt0 = b * TT + t0;

    // ---- v window staging (72 rows x 256 bf16 = 2304 uint4 slots) ----
    const ushort* vb = v + (size_t)b * TT * DD + h * 256;
    #pragma unroll
    for (int i = 0; i < 5; i++) {
        int c = i * 512 + tid;
        if (c < HB2 * 32) {
            int r = c >> 5;
            int cir = c & 31;
            int t = t0 - HALO + r;
            uint4 val = make_uint4(0, 0, 0, 0);
            if (t >= 0 && t < TT)
                val = *(const uint4*)(vb + (size_t)t * DD + cir * 8);
            *(uint4*)(&vs[r][cir * 8]) = val;
        }
    }

    // ---- QK GEMM: logits[32][64] = reluq rows x W2Tph[h]^T, K=1024 ----
    // 8 waves, wave (wv>>2, wv&3) owns one 16x16 frag: rows wr..wr+15 (q),
    // cols wc..wc+15 (logit dims).
    const int wv = tid >> 6;          // 0..7
    const int ln = tid & 63;
    const int wr = (wv >> 2) * 16;    // q-row offset: 0/16
    const int wc = (wv & 3) * 16;     // logit-dim offset: 0/16/32/48
    const int l15 = ln & 15;
    const int lq  = ln >> 4;
    const int rsub = ln >> 3;
    const int cg   = (ln & 7) ^ rsub;           // swizzled global chunk
    const int fx = l15 & 7;

    // staging roles: waves 0-3 stage qs slot wv (rows wv*8..+7) AND ws2 slot wv;
    // waves 4-7 stage ws2 slot wv only. Row bases are multiples of 8 (swizzle ok).
    const int qrow = (wv & 3) * 8 + rsub;       // safe for all waves (issued by 0-3)
    const ushort* gA = reluq + (size_t)(bt0 + qrow) * DD + cg * 8;
    const ushort* gB = W2Tph + ((size_t)h * 64 + wv * 8 + rsub) * DD + cg * 8;

    f32x4 acc = (f32x4){0.f, 0.f, 0.f, 0.f};

    auto STAGEQ = [&](int buf, int kk) {
        if (wv < 4) {
            __builtin_amdgcn_global_load_lds(
                (const __attribute__((address_space(1))) void*)(gA + kk),
                (__attribute__((address_space(3))) void*)(&qs[(size_t)buf * TB2 * 64 + ((wv & 3) * 8) * 64]),
                16, 0, 0);
        }
        __builtin_amdgcn_global_load_lds(
            (const __attribute__((address_space(1))) void*)(gB + kk),
            (__attribute__((address_space(3))) void*)(&ws2[(size_t)buf * 64 * 64 + (wv * 8) * 64]),
            16, 0, 0);
    };
    auto COMPQ = [&](int buf) {
        #pragma unroll
        for (int s = 0; s < 2; s++) {
            const int ca = ((s * 4 + lq) ^ fx) * 8;
            bf16x8 a  = *(const bf16x8*)&qs[(size_t)buf * TB2 * 64 + (wr + l15) * 64 + ca];
            bf16x8 bb = *(const bf16x8*)&ws2[(size_t)buf * 64 * 64 + (wc + l15) * 64 + ca];
            acc = __builtin_amdgcn_mfma_f32_16x16x32_bf16(a, bb, acc, 0, 0, 0);
        }
    };

    int cur = 0;
    STAGEQ(0, 0);
    __syncthreads();
    for (int t = 0; t < 16; ++t) {
        const bool more = (t + 1 < 16);
        if (more) STAGEQ(cur ^ 1, (t + 1) * 64);
        COMPQ(cur);
        if (more) __syncthreads();
        cur ^= 1;
    }
    // frag -> Ls: q-row = wr + lq*4 + r, logit col = wc + l15
    #pragma unroll
    for (int r = 0; r < 4; r++)
        Ls[wr + lq * 4 + r][wc + l15] = acc[r];
    __syncthreads();

    // ---- softmax over cols 0..20 (scale0) and 21..61 (scale1) -> cw ----
    if (tid < TB2) {
        float s0 = scale_w[0], s1 = scale_w[1];
        float mm = fmaxf(s0, s1);
        float e0 = __expf(s0 - mm), e1 = __expf(s1 - mm);
        float inv01 = 1.0f / (e0 + e1);
        float sw0 = e0 * inv01, sw1 = e1 * inv01;

        float w0[C0], w1[C1];
        {
            float m = -1e30f;
            #pragma unroll
            for (int j = 0; j < C0; j++) { w0[j] = Ls[tid][j]; m = fmaxf(m, w0[j]); }
            float s = 0.0f;
            #pragma unroll
            for (int j = 0; j < C0; j++) { w0[j] = __expf(w0[j] - m); s += w0[j]; }
            float inv = sw0 / s;
            #pragma unroll
            for (int j = 0; j < C0; j++) w0[j] *= inv;
        }
        {
            float m = -1e30f;
            #pragma unroll
            for (int j = 0; j < C1; j++) { w1[j] = Ls[tid][C0 + j]; m = fmaxf(m, w1[j]); }
            float s = 0.0f;
            #pragma unroll
            for (int j = 0; j < C1; j++) { w1[j] = __expf(w1[j] - m); s += w1[j]; }
            float inv = sw1 / s;
            #pragma unroll
            for (int j = 0; j < C1; j++) w1[j] *= inv;
        }
        #pragma unroll
        for (int o = 0; o < C1; o++) {
            float w = w1[o];
            if (o >= 10 && o <= 30) w += w0[o - 10];
            cw[tid][o] = w;
        }
    }
    __syncthreads();

    // ---- window sum: 8 wave-groups x 4 rows, 64 d-chunks ----
    const int tq = tid >> 6;          // 0..7
    const int dg = tid & 63;
    const int d  = dg * 4;

    #pragma unroll
    for (int tloc = 0; tloc < 4; tloc++) {
        const int tp = tq * 4 + tloc;
        f32x4 o4acc = {0.f, 0.f, 0.f, 0.f};
        #pragma unroll
        for (int o = 0; o < C1; o++) {
            float w = cw[tp][o];
            ushort4 vv = *(const ushort4*)(&vs[tp + o][d]);
            o4acc[0] = fmaf(w, bf2f(vv.x), o4acc[0]);
            o4acc[1] = fmaf(w, bf2f(vv.y), o4acc[1]);
            o4acc[2] = fmaf(w, bf2f(vv.z), o4acc[2]);
            o4acc[3] = fmaf(w, bf2f(vv.w), o4acc[3]);
        }
        const int bt = bt0 + tp;
        ushort4 o4;
        o4.x = f2bf(o4acc[0]); o4.y = f2bf(o4acc[1]);
        o4.z = f2bf(o4acc[2]); o4.w = f2bf(o4acc[3]);
        *(ushort4*)(x + (size_t)bt * DD + h * 256 + d) = o4;
    }
}

// ---------------------------------- launch ----------------------------------
extern "C" void kernel_launch(void* const* d_in, const int* in_sizes, int n_in,
                              void* d_out, int out_size, void* d_ws, size_t ws_size,
                              hipStream_t stream)
{
    const float* query   = (const float*)d_in[0];
    const float* W_qv    = (const float*)d_in[3];
    const float* W2_0    = (const float*)d_in[4];
    const float* W2_1    = (const float*)d_in[5];
    const float* scale_w = (const float*)d_in[6];
    const float* W_out   = (const float*)d_in[7];
    float* out = (float*)d_out;

    // Workspace layout
    char* ws = (char*)d_ws;
    ushort* W2Tph    = (ushort*)ws;                 ws += (size_t)4 * 64 * DD * 2;      // 0.5 MB
    ushort* WoutT    = (ushort*)ws;                 ws += (size_t)DD * DD * 2;          // 2 MB
    ushort* query_bf = (ushort*)ws;                 ws += (size_t)BT * DD * 2;          // 8 MB
    ushort* WqvT     = (ushort*)ws;                 ws += (size_t)2 * DD * DD * 2;      // 4 MB
    ushort* reluq    = (ushort*)ws;                 ws += (size_t)BT * DD * 2;          // 8 MB
    ushort* vbuf     = (ushort*)ws;                 ws += (size_t)BT * DD * 2;          // 8 MB
    ushort* xbuf     = (ushort*)ws;                 ws += (size_t)BT * DD * 2;          // 8 MB

    // 0) all conversions in one launch
    convert_all<<<R4, 256, 0, stream>>>(query, query_bf, W_qv, WqvT,
                                        W_out, WoutT, W2_0, W2_1, W2Tph);

    // 1) qv GEMM: [4096,1024]x[1024,2048] -> reluq + vbuf (512 blocks x 512 thr)
    {   dim3 grid(2 * DD / 128, BT / 128, 1);
        gemm_mfma<128, 4><<<grid, 512, 0, stream>>>(query_bf, WqvT, DD, DD,
                                                    nullptr, reluq, vbuf, 2, 0); }
    // 2) fused logits + softmax + sliding window -> xbuf (512 blocks x 512 thr)
    attn_fused_kernel<<<512, 512, LDS_TOTAL, stream>>>(reluq, W2Tph, vbuf,
                                                       scale_w, xbuf);

    // 3) out GEMM: x x WoutT -> out f32 (512 blocks, 3 blocks/CU via MINW=6)
    {   dim3 grid(DD / 64, BT / 128, 1);
        gemm_mfma<64, 6><<<grid, 512, 0, stream>>>(xbuf, WoutT, DD, DD,
                                                   out, nullptr, nullptr, 0, DD); }
}

// Round 10
// 166.306 us; speedup vs baseline: 1.1762x; 1.1762x over previous
//
#include <hip/hip_runtime.h>
#include <hip/hip_bf16.h>
#include <math.h>

// Problem dims (fixed by reference)
#define BB 4
#define TT 1024
#define DD 1024
#define HPS 4          // heads per scale
#define C0 21
#define C1 41
#define N0 (HPS * C0)  // 84
#define N1 (HPS * C1)  // 164
#define BT (BB * TT)   // 4096
#define TB2 32         // t-tile for window kernel (512 blocks -> 2/CU)
#define HALO 20
#define HB2 (TB2 + 2 * HALO)  // 72 rows staged

typedef unsigned int uint;
typedef __bf16 bf16x8 __attribute__((ext_vector_type(8)));
typedef float f32x4 __attribute__((ext_vector_type(4)));

__device__ __forceinline__ ushort f2bf(float f) {
    union { float f; uint u; } v; v.f = f;
    uint u = v.u;
    uint r = (u + 0x7FFFu + ((u >> 16) & 1u)) >> 16;
    return (ushort)r;
}
__device__ __forceinline__ float bf2f(ushort s) {
    union { uint u; float f; } v; v.u = ((uint)s) << 16;
    return v.f;
}

// ---------------- fused conversion kernel (query + weights) ----------------
#define RQ  4096
#define R1  (RQ + 2048)
#define R2  (R1 + 1024)
#define R3  (R2 + 96)
#define R4  (R3 + 192)

// Transpose [K][Nin] f32 -> bf16 [row][K] where row = (n/hs)*64 + roff + n%hs.
// hs >= Nin gives linear row = n (W_qv, W_out). For W2 the per-head remap packs
// head h's columns into rows h*64 + roff.. for the fused attn kernel.
__device__ __forceinline__ void transpose_tile(
    const float* __restrict__ in, ushort* __restrict__ out,
    int K, int Nin, int nx, int ky, int tid, int hs, int roff)
{
    __shared__ float tile[32][33];
    const int tx = tid & 31;
    const int ty = tid >> 5;   // 0..7
    const int n0 = nx * 32;
    const int k0 = ky * 32;
    #pragma unroll
    for (int i = 0; i < 4; i++) {
        int k = k0 + ty + i * 8;
        int n = n0 + tx;
        float v = (k < K && n < Nin) ? in[(size_t)k * Nin + n] : 0.0f;
        tile[ty + i * 8][tx] = v;
    }
    __syncthreads();
    #pragma unroll
    for (int i = 0; i < 4; i++) {
        int n = n0 + ty + i * 8;
        int k = k0 + tx;
        if (n < Nin && k < K) {
            int row = (n / hs) * 64 + roff + (n % hs);
            out[(size_t)row * K + k] = f2bf(tile[tx][ty + i * 8]);
        }
    }
}

__global__ __launch_bounds__(256) void convert_all(
    const float* __restrict__ query, ushort* __restrict__ query_bf,
    const float* __restrict__ W_qv,  ushort* __restrict__ WqvT,
    const float* __restrict__ W_out, ushort* __restrict__ WoutT,
    const float* __restrict__ W2_0, const float* __restrict__ W2_1,
    ushort* __restrict__ W2Tph)
{
    const int blk = blockIdx.x;
    const int tid = threadIdx.x;
    if (blk < RQ) {
        int i = blk * 1024 + tid * 4;
        float4 v = *(const float4*)(query + i);
        ushort4 o;
        o.x = f2bf(v.x); o.y = f2bf(v.y); o.z = f2bf(v.z); o.w = f2bf(v.w);
        *(ushort4*)(query_bf + i) = o;
    } else if (blk < R1) {
        int idx = blk - RQ;                // 64 x 32 tiles, linear rows
        transpose_tile(W_qv, WqvT, DD, 2 * DD, idx & 63, idx >> 6, tid, 2 * DD, 0);
    } else if (blk < R2) {
        int idx = blk - R1;                // 32 x 32 tiles, linear rows
        transpose_tile(W_out, WoutT, DD, DD, idx & 31, idx >> 5, tid, DD, 0);
    } else if (blk < R3) {
        int idx = blk - R2;                // 3 x 32: scale0 -> rows h*64 + 0..20
        transpose_tile(W2_0, W2Tph, DD, N0, idx % 3, idx / 3, tid, C0, 0);
    } else {
        int idx = blk - R3;                // 6 x 32: scale1 -> rows h*64 + 21..61
        transpose_tile(W2_1, W2Tph, DD, N1, idx % 6, idx / 6, tid, C1, C0);
    }
}

// XCD-chunked bijective tile remap (T1). Requires ntile % 8 == 0.
__device__ __forceinline__ int xcd_chunk(int blk, int nblk) {
    return (blk & 7) * (nblk >> 3) + (blk >> 3);
}

// ------ bf16 MFMA GEMM, 8-wave (512-thr) block, 128xNT tile, BK=64 dbuf ------
// A: [M][K] bf16 row-major. Bt: [N][K] bf16 row-major (both via global_load_lds
// with pre-swizzled source). K,klen multiples of 64.
// 8 waves in 2(M) x 4(N); wave owns 64 x NT/4. MINW = min waves/EU:
// NT=128 (64 KB LDS) -> MINW=4 (2 blocks/CU, LDS-capped);
// NT=64 (48 KB LDS) -> MINW=6 (3 blocks/CU, VGPR cap 85 — kernel needs ~70,
// validated by R9 accounting: out GEMM improved ~6 us under this bound).
// LDS per buffer: [row][slot 0..7][8 ushort]; slot (r,c) holds global chunk
// c^(r&7). Fragment read xor fx=l15&7 -> 2-way bank aliasing (free).
// mode 0: Cf[row*ldc+col] = acc
// mode 2: col<DD -> Cb[row*DD+col]=bf16(relu(acc)); else Cv[row*DD+col-DD]=bf16(acc)
template<int NT, int MINW>
__global__ __launch_bounds__(512, MINW) void gemm_mfma(
    const ushort* __restrict__ A, const ushort* __restrict__ Bt,
    int K, int klen,
    float* __restrict__ Cf, ushort* __restrict__ Cb, ushort* __restrict__ Cv,
    int mode, int ldc)
{
    constexpr int MT = 128;
    constexpr int MR = 4;          // 64 / 16
    constexpr int NR = NT / 64;    // wave N-frags: NT=128 -> 2, NT=64 -> 1
    __shared__ ushort As[2][MT * 64];   // 2 x 16 KB
    __shared__ ushort Bs[2][NT * 64];   // 2 x (16 or 8) KB

    const int tid = threadIdx.x;
    const int wv  = tid >> 6;          // 0..7
    const int ln  = tid & 63;

    const int ntile = gridDim.x * gridDim.y;
    const int tile  = xcd_chunk(blockIdx.y * gridDim.x + blockIdx.x, ntile);
    const int bx = tile % gridDim.x;
    const int by = tile / gridDim.x;
    const int row0 = by * MT;
    const int col0 = bx * NT;

    const int wr = (wv >> 2) * 64;        // wave M offset: 0/64
    const int wc = (wv & 3) * (NT / 4);   // wave N offset
    const int l15 = ln & 15;
    const int lq  = ln >> 4;              // 0..3

    f32x4 acc[MR][NR];
    #pragma unroll
    for (int i = 0; i < MR; i++)
        #pragma unroll
        for (int j = 0; j < NR; j++)
            acc[i][j] = (f32x4){0.f, 0.f, 0.f, 0.f};

    const int rsub = ln >> 3;             // 0..7
    const int cg   = (ln & 7) ^ rsub;     // pre-swizzled global chunk
    const ushort* gA = A  + (size_t)(row0 + wv * 8 + rsub) * K + cg * 8;
    const ushort* gB = Bt + (size_t)(col0 + wv * 8 + rsub) * K + cg * 8;
    const int fx = l15 & 7;
    const int nt = klen / 64;

    auto STAGE = [&](int buf, int kk) {
        #pragma unroll
        for (int i = 0; i < 2; i++) {     // A: 2 instrs cover 128 rows
            __builtin_amdgcn_global_load_lds(
                (const __attribute__((address_space(1))) void*)(gA + (size_t)i * 64 * K + kk),
                (__attribute__((address_space(3))) void*)(&As[buf][(i * 64 + wv * 8) * 64]),
                16, 0, 0);
        }
        #pragma unroll
        for (int i = 0; i < NT / 64; i++) {  // B: NT/64 instrs
            __builtin_amdgcn_global_load_lds(
                (const __attribute__((address_space(1))) void*)(gB + (size_t)i * 64 * K + kk),
                (__attribute__((address_space(3))) void*)(&Bs[buf][(i * 64 + wv * 8) * 64]),
                16, 0, 0);
        }
    };

    auto COMPUTE = [&](int buf) {
        #pragma unroll
        for (int s = 0; s < 2; s++) {
            const int ca = ((s * 4 + lq) ^ fx) * 8;
            bf16x8 af[MR], bfr[NR];
            #pragma unroll
            for (int mi = 0; mi < MR; mi++)
                af[mi] = *(const bf16x8*)&As[buf][(wr + mi * 16 + l15) * 64 + ca];
            #pragma unroll
            for (int ni = 0; ni < NR; ni++)
                bfr[ni] = *(const bf16x8*)&Bs[buf][(wc + ni * 16 + l15) * 64 + ca];
            #pragma unroll
            for (int mi = 0; mi < MR; mi++)
                #pragma unroll
                for (int ni = 0; ni < NR; ni++)
                    acc[mi][ni] = __builtin_amdgcn_mfma_f32_16x16x32_bf16(
                        af[mi], bfr[ni], acc[mi][ni], 0, 0, 0);
        }
    };

    int cur = 0;
    STAGE(0, 0);
    __syncthreads();
    for (int t = 0; t < nt; ++t) {
        const bool more = (t + 1 < nt);
        if (more) STAGE(cur ^ 1, (t + 1) * 64);
        COMPUTE(cur);
        if (more) __syncthreads();
        cur ^= 1;
    }

    // Epilogue. D layout: col = lane&15, row = (lane>>4)*4 + reg.
    #pragma unroll
    for (int mi = 0; mi < MR; mi++) {
        #pragma unroll
        for (int ni = 0; ni < NR; ni++) {
            #pragma unroll
            for (int r = 0; r < 4; r++) {
                int row = row0 + wr + mi * 16 + lq * 4 + r;
                int col = col0 + wc + ni * 16 + l15;
                float v = acc[mi][ni][r];
                if (mode == 0) {
                    Cf[(size_t)row * ldc + col] = v;
                } else {
                    if (col < DD) Cb[(size_t)row * DD + col] = f2bf(fmaxf(v, 0.0f));
                    else          Cv[(size_t)row * DD + (col - DD)] = f2bf(v);
                }
            }
        }
    }
}

// ---- fused logits + softmax + sliding-window kernel (R7 256-thread version) ----
// 512 blocks = (b, t-tile of 32, head), 256 threads, ~75 KB dynamic LDS (2/CU).
// NOTE: no min-waves bound — R9's __launch_bounds__(512,4) variant capped VGPRs
// at 64 and spilled the 62-float softmax arrays to scratch (110 MB writes/disp,
// attn 15 -> 53 us). 256 threads + unconstrained allocator = no spill.
#define LOFF_VS 0
#define LOFF_QS (LOFF_VS + HB2 * 256 * 2)            // 36864
#define LOFF_WS (LOFF_QS + 2 * TB2 * 64 * 2)         // +8192 = 45056
#define LOFF_LS (LOFF_WS + 2 * 64 * 64 * 2)          // +16384 = 61440
#define LOFF_CW (LOFF_LS + TB2 * 65 * 4)             // +8320 = 69760
#define LDS_TOTAL (LOFF_CW + TB2 * 42 * 4)           // +5376 = 75136

__global__ __launch_bounds__(256) void attn_fused_kernel(
    const ushort* __restrict__ reluq,
    const ushort* __restrict__ W2Tph,   // [4][64][1024] bf16
    const ushort* __restrict__ v,
    const float* __restrict__ scale_w,
    ushort* __restrict__ x)
{
    extern __shared__ __attribute__((aligned(16))) char smem[];
    ushort (*vs)[256] = (ushort (*)[256])(smem + LOFF_VS);
    ushort* qs = (ushort*)(smem + LOFF_QS);          // [2][32*64]
    ushort* ws2 = (ushort*)(smem + LOFF_WS);         // [2][64*64]
    float  (*Ls)[65] = (float (*)[65])(smem + LOFF_LS);
    float  (*cw)[42] = (float (*)[42])(smem + LOFF_CW);

    const int blk = blockIdx.x;       // 512 blocks
    const int h  = blk & 3;
    const int tt = (blk >> 2) & 31;
    const int b  = blk >> 7;
    const int t0 = tt * TB2;
    const int tid = threadIdx.x;
    const int bt0 = b * TT + t0;

    // ---- v window staging (72 rows x 256 bf16) ----
    const ushort* vb = v + (size_t)b * TT * DD + h * 256;
    #pragma unroll
    for (int i = 0; i < 9; i++) {
        int c = i * 256 + tid;
        int r = c >> 5;
        int cir = c & 31;
        int t = t0 - HALO + r;
        uint4 val = make_uint4(0, 0, 0, 0);
        if (t >= 0 && t < TT)
            val = *(const uint4*)(vb + (size_t)t * DD + cir * 8);
        *(uint4*)(&vs[r][cir * 8]) = val;
    }

    // ---- QK GEMM: logits[32][64] = reluq rows x W2Tph[h]^T, K=1024 ----
    const int wv = tid >> 6;          // 0..3
    const int ln = tid & 63;
    const int wr = (wv >> 1) * 16;    // wave M offset: 0/16
    const int wc = (wv & 1) * 32;     // wave N offset: 0/32
    const int l15 = ln & 15;
    const int lq  = ln >> 4;
    const int rsub = ln >> 3;
    const int cg   = (ln & 7) ^ rsub;           // swizzled global chunk
    const int fx = l15 & 7;

    const ushort* gA = reluq + (size_t)(bt0 + wv * 8 + rsub) * DD + cg * 8;
    const ushort* gB = W2Tph + ((size_t)h * 64 + wv * 16 + rsub) * DD + cg * 8;

    f32x4 acc[2];
    acc[0] = (f32x4){0.f, 0.f, 0.f, 0.f};
    acc[1] = (f32x4){0.f, 0.f, 0.f, 0.f};

    auto STAGEQ = [&](int buf, int kk) {
        __builtin_amdgcn_global_load_lds(
            (const __attribute__((address_space(1))) void*)(gA + kk),
            (__attribute__((address_space(3))) void*)(&qs[(size_t)buf * TB2 * 64 + (wv * 8) * 64]),
            16, 0, 0);
        #pragma unroll
        for (int i = 0; i < 2; i++) {
            __builtin_amdgcn_global_load_lds(
                (const __attribute__((address_space(1))) void*)(gB + (size_t)i * 8 * DD + kk),
                (__attribute__((address_space(3))) void*)(&ws2[(size_t)buf * 64 * 64 + (wv * 16 + i * 8) * 64]),
                16, 0, 0);
        }
    };
    auto COMPQ = [&](int buf) {
        #pragma unroll
        for (int s = 0; s < 2; s++) {
            const int ca = ((s * 4 + lq) ^ fx) * 8;
            bf16x8 a = *(const bf16x8*)&qs[(size_t)buf * TB2 * 64 + (wr + l15) * 64 + ca];
            #pragma unroll
            for (int ni = 0; ni < 2; ni++) {
                bf16x8 bb = *(const bf16x8*)&ws2[(size_t)buf * 64 * 64 + (wc + ni * 16 + l15) * 64 + ca];
                acc[ni] = __builtin_amdgcn_mfma_f32_16x16x32_bf16(a, bb, acc[ni], 0, 0, 0);
            }
        }
    };

    int cur = 0;
    STAGEQ(0, 0);
    __syncthreads();
    for (int t = 0; t < 16; ++t) {
        const bool more = (t + 1 < 16);
        if (more) STAGEQ(cur ^ 1, (t + 1) * 64);
        COMPQ(cur);
        if (more) __syncthreads();
        cur ^= 1;
    }
    #pragma unroll
    for (int ni = 0; ni < 2; ni++)
        #pragma unroll
        for (int r = 0; r < 4; r++)
            Ls[wr + lq * 4 + r][wc + ni * 16 + l15] = acc[ni][r];
    __syncthreads();

    // ---- softmax over cols 0..20 (scale0) and 21..61 (scale1) -> cw ----
    if (tid < TB2) {
        float s0 = scale_w[0], s1 = scale_w[1];
        float mm = fmaxf(s0, s1);
        float e0 = __expf(s0 - mm), e1 = __expf(s1 - mm);
        float inv01 = 1.0f / (e0 + e1);
        float sw0 = e0 * inv01, sw1 = e1 * inv01;

        float w0[C0], w1[C1];
        {
            float m = -1e30f;
            #pragma unroll
            for (int j = 0; j < C0; j++) { w0[j] = Ls[tid][j]; m = fmaxf(m, w0[j]); }
            float s = 0.0f;
            #pragma unroll
            for (int j = 0; j < C0; j++) { w0[j] = __expf(w0[j] - m); s += w0[j]; }
            float inv = sw0 / s;
            #pragma unroll
            for (int j = 0; j < C0; j++) w0[j] *= inv;
        }
        {
            float m = -1e30f;
            #pragma unroll
            for (int j = 0; j < C1; j++) { w1[j] = Ls[tid][C0 + j]; m = fmaxf(m, w1[j]); }
            float s = 0.0f;
            #pragma unroll
            for (int j = 0; j < C1; j++) { w1[j] = __expf(w1[j] - m); s += w1[j]; }
            float inv = sw1 / s;
            #pragma unroll
            for (int j = 0; j < C1; j++) w1[j] *= inv;
        }
        #pragma unroll
        for (int o = 0; o < C1; o++) {
            float w = w1[o];
            if (o >= 10 && o <= 30) w += w0[o - 10];
            cw[tid][o] = w;
        }
    }
    __syncthreads();

    // ---- window sum ----
    const int tq = tid >> 6;
    const int dg = tid & 63;
    const int d  = dg * 4;

    for (int tloc = 0; tloc < 8; tloc++) {
        const int tp = tq * 8 + tloc;
        f32x4 o4acc = {0.f, 0.f, 0.f, 0.f};
        #pragma unroll
        for (int o = 0; o < C1; o++) {
            float w = cw[tp][o];
            ushort4 vv = *(const ushort4*)(&vs[tp + o][d]);
            o4acc[0] = fmaf(w, bf2f(vv.x), o4acc[0]);
            o4acc[1] = fmaf(w, bf2f(vv.y), o4acc[1]);
            o4acc[2] = fmaf(w, bf2f(vv.z), o4acc[2]);
            o4acc[3] = fmaf(w, bf2f(vv.w), o4acc[3]);
        }
        const int bt = bt0 + tp;
        ushort4 o4;
        o4.x = f2bf(o4acc[0]); o4.y = f2bf(o4acc[1]);
        o4.z = f2bf(o4acc[2]); o4.w = f2bf(o4acc[3]);
        *(ushort4*)(x + (size_t)bt * DD + h * 256 + d) = o4;
    }
}

// ---------------------------------- launch ----------------------------------
extern "C" void kernel_launch(void* const* d_in, const int* in_sizes, int n_in,
                              void* d_out, int out_size, void* d_ws, size_t ws_size,
                              hipStream_t stream)
{
    const float* query   = (const float*)d_in[0];
    const float* W_qv    = (const float*)d_in[3];
    const float* W2_0    = (const float*)d_in[4];
    const float* W2_1    = (const float*)d_in[5];
    const float* scale_w = (const float*)d_in[6];
    const float* W_out   = (const float*)d_in[7];
    float* out = (float*)d_out;

    // Workspace layout
    char* ws = (char*)d_ws;
    ushort* W2Tph    = (ushort*)ws;                 ws += (size_t)4 * 64 * DD * 2;      // 0.5 MB
    ushort* WoutT    = (ushort*)ws;                 ws += (size_t)DD * DD * 2;          // 2 MB
    ushort* query_bf = (ushort*)ws;                 ws += (size_t)BT * DD * 2;          // 8 MB
    ushort* WqvT     = (ushort*)ws;                 ws += (size_t)2 * DD * DD * 2;      // 4 MB
    ushort* reluq    = (ushort*)ws;                 ws += (size_t)BT * DD * 2;          // 8 MB
    ushort* vbuf     = (ushort*)ws;                 ws += (size_t)BT * DD * 2;          // 8 MB
    ushort* xbuf     = (ushort*)ws;                 ws += (size_t)BT * DD * 2;          // 8 MB

    // 0) all conversions in one launch
    convert_all<<<R4, 256, 0, stream>>>(query, query_bf, W_qv, WqvT,
                                        W_out, WoutT, W2_0, W2_1, W2Tph);

    // 1) qv GEMM: [4096,1024]x[1024,2048] -> reluq + vbuf (512 blocks x 512 thr)
    {   dim3 grid(2 * DD / 128, BT / 128, 1);
        gemm_mfma<128, 4><<<grid, 512, 0, stream>>>(query_bf, WqvT, DD, DD,
                                                    nullptr, reluq, vbuf, 2, 0); }
    // 2) fused logits + softmax + sliding window -> xbuf (512 blocks x 256 thr)
    attn_fused_kernel<<<512, 256, LDS_TOTAL, stream>>>(reluq, W2Tph, vbuf,
                                                       scale_w, xbuf);

    // 3) out GEMM: x x WoutT -> out f32 (512 blocks, 3 blocks/CU via MINW=6)
    {   dim3 grid(DD / 64, BT / 128, 1);
        gemm_mfma<64, 6><<<grid, 512, 0, stream>>>(xbuf, WoutT, DD, DD,
                                                   out, nullptr, nullptr, 0, DD); }
}